// Round 15
// baseline (215.240 us; speedup 1.0000x reference)
//
#include <hip/hip_runtime.h>
#include <hip/hip_bf16.h>

#define Bn 2
#define Tn 12
#define Hn 80
#define Wn 120
#define CIN 6
#define SITES (Hn * Wn)          // 9600
#define HSZ (4 * SITES * 32)     // 1228800 elements per bf16 state field
#define GRID 512                 // 4 fields x 16 yb x 8 seg  (= 2 blocks/CU, all co-resident)
#define BLK 256

#define NA_D (48 * 64 * 8)       // gates operand-order B set, per dir (24576 shorts)
#define NB_D (24 * 64 * 8)       // candidate set per dir (12288 shorts)
#define NA (2 * NA_D)
#define NB (2 * NB_D)
#define NPX (Bn * Tn * SITES)
#define PREP_TOT (NA + NB + NPX) // 304128

#define ZSTR 34                  // z_l/hpub site stride (floats): bank=(2*site+ch)%32 -> 2-way

typedef __attribute__((ext_vector_type(8))) short short8;
typedef __attribute__((ext_vector_type(4))) float f32x4;

__device__ __forceinline__ short f2bf(float f) {
    union { __hip_bfloat16 h; short s; } u;
    u.h = __float2bfloat16(f);
    return u.s;
}
__device__ __forceinline__ float bf2f(short s) {
    union { float f; unsigned u; } u;
    u.u = ((unsigned)(unsigned short)s) << 16;
    return u.f;
}
// v_rcp_f32-based (~1ulp): full fp32 divide is ~10 instrs of div_scale/fmas/fixup
__device__ __forceinline__ float fast_sigmoid(float v) {
    return __builtin_amdgcn_rcpf(1.f + __expf(-v));
}
__device__ __forceinline__ float fast_tanh(float v) {
    v = fminf(fmaxf(v, -15.f), 15.f);
    float e = __expf(2.f * v);
    return (e - 1.f) * __builtin_amdgcn_rcpf(e + 1.f);
}

// ---- coherent (L2-bypass) h-state access: agent-scope relaxed atomics ----
__device__ __forceinline__ short8 h_load16(const short* p) {
    union { unsigned long long q[2]; short8 v; } u;
    u.q[0] = __hip_atomic_load((const unsigned long long*)p,
                               __ATOMIC_RELAXED, __HIP_MEMORY_SCOPE_AGENT);
    u.q[1] = __hip_atomic_load((const unsigned long long*)(p + 4),
                               __ATOMIC_RELAXED, __HIP_MEMORY_SCOPE_AGENT);
    return u.v;
}
__device__ __forceinline__ void h_store16(short* p, short8 v) {
    union { short8 v; unsigned long long q[2]; } u; u.v = v;
    __hip_atomic_store((unsigned long long*)p, u.q[0],
                       __ATOMIC_RELAXED, __HIP_MEMORY_SCOPE_AGENT);
    __hip_atomic_store((unsigned long long*)(p + 4), u.q[1],
                       __ATOMIC_RELAXED, __HIP_MEMORY_SCOPE_AGENT);
}

// ---- h_l LDS bank-conflict swizzle (bijective; applied to all h_l accesses) ----
__device__ __forceinline__ int swz16(int i) { return i ^ (((i >> 5) & 7) << 3); }

// ---- prologue: expand weights to MFMA-operand order + pack x to padded bf16x8 ----
__global__ __launch_bounds__(BLK) void prep_kernel(
    const float* __restrict__ Wzr_f, const float* __restrict__ Wzr_b,
    const float* __restrict__ Wh_f,  const float* __restrict__ Wh_b,
    const float* __restrict__ Wx_f,  const float* __restrict__ Wx_b,
    const float* __restrict__ x,
    short* __restrict__ bopA, short* __restrict__ bopB, short* __restrict__ xb8,
    unsigned* __restrict__ flags)
{
    int i = blockIdx.x * BLK + threadIdx.x;
    if (i < GRID) flags[i << 5] = 0;   // reset per-block step flags each replay
    if (i < NA) {
        int dir = i / NA_D; int r = i % NA_D;
        int f = r / 512; int lane = (r % 512) / 8; int j = r % 8;
        int q = lane >> 4, n = lane & 15;
        int chunk = f >> 2, nt = f & 3;
        float v = 0.f;
        if (chunk < 3) {
            int tap = chunk * 4 + q;
            if (tap < 9 && j < 6) v = (dir ? Wx_b : Wx_f)[(tap * CIN + j) * 96 + nt * 16 + n];
        } else {
            int tap = chunk - 3;
            v = (dir ? Wzr_b : Wzr_f)[(tap * 32 + q * 8 + j) * 64 + nt * 16 + n];
        }
        bopA[i] = f2bf(v);
    } else if (i < NA + NB) {
        int ii = i - NA;
        int dir = ii / NB_D; int r = ii % NB_D;
        int f = r / 512; int lane = (r % 512) / 8; int j = r % 8;
        int q = lane >> 4, n = lane & 15;
        int chunk = f >> 1, ntc = f & 1;
        float v = 0.f;
        if (chunk < 3) {
            int tap = chunk * 4 + q;
            if (tap < 9 && j < 6) v = (dir ? Wx_b : Wx_f)[(tap * CIN + j) * 96 + 64 + ntc * 16 + n];
        } else {
            int tap = chunk - 3;
            v = (dir ? Wh_b : Wh_f)[(tap * 32 + q * 8 + j) * 32 + ntc * 16 + n];
        }
        bopB[ii] = f2bf(v);
    } else if (i < PREP_TOT) {
        int p = i - NA - NB;
        const float* xp = x + (size_t)p * CIN;
        short v[8];
        #pragma unroll
        for (int c = 0; c < CIN; c++) v[c] = f2bf(xp[c]);
        v[6] = 0; v[7] = 0;
        *(short8*)&xb8[(size_t)p * 8] = *(short8*)v;
    }
}

// ---- persistent fused GRU, neighbor-local synchronization ----
// LDS: bA 48K + rh 10080 + z/hpub 10880 + h-tile 11520 = 81632 B -> 2 blocks/CU.
// Round-15: the phase-A x-part MFMA (no neighbor dependency) runs BEFORE the
// neighbor wait, so the flag-poll latency hides under 12 MFMAs; phase-B x loads
// are also issued pre-wait and consumed from registers.
__global__ __launch_bounds__(BLK, 2) void step_all(
    const short* __restrict__ xb8,
    const short* __restrict__ bopA, const short* __restrict__ bopB,
    const float* __restrict__ b_f, const float* __restrict__ b_b,
    short* __restrict__ hb0, short* __restrict__ hb1,
    float* __restrict__ out, unsigned* __restrict__ flags)
{
    __shared__ __align__(16) short bA_l[NA_D];        // 49152 B
    __shared__ __align__(16) short rh_l[126 * 40];    // 10080 B (r*h bf16, halo 7x18)
    __shared__ __align__(16) float z_l[80 * ZSTR];    // 10880 B (z fp32 | hpub overlay)
    __shared__ __align__(16) short h_l[9 * 20 * 32];  // 11520 B (swizzled)

    int tid = threadIdx.x, bid = blockIdx.x;
    int seg = bid & 7;
    int t1  = bid >> 3;
    int yb  = t1 & 15;
    int field = t1 >> 4;
    int dir = field >> 1, b = field & 1;
    int y0 = yb * 5, x0 = seg * 16;

    // stage this-direction gate B-set into LDS once
    {
        const short* src = bopA + dir * NA_D;
        #pragma unroll
        for (int it = 0; it < NA_D / (BLK * 8); it++) {
            int i = (it * BLK + tid) * 8;
            *(short8*)&bA_l[i] = *(const short8*)&src[i];
        }
    }
    // zero-init h tile (out-of-image sites rely on staying zero forever)
    for (int c = tid; c < 720; c += BLK) *(short8*)&h_l[c * 8] = (short8)(short)0;

    const short* bB   = bopB + dir * NB_D;
    const float* bias = dir ? b_b : b_f;
    short* hfield0 = hb0 + (size_t)field * SITES * 32;
    short* hfield1 = hb1 + (size_t)field * SITES * 32;

    int wid = tid >> 6, lane = tid & 63;
    int n = lane & 15, q = lane >> 4, q8 = q * 8;

    // ---- neighbor flags ----
    unsigned* myflag = flags + (bid << 5);
    const unsigned* nflag = nullptr;
    if (tid < 8) {
        int k = tid + (tid >= 4);
        int ny = yb + k / 3 - 1, nx = seg + k % 3 - 1;
        if (ny >= 0 && ny < 16 && nx >= 0 && nx < 8)
            nflag = flags + ((unsigned)((field << 7) | (ny << 3) | nx) << 5);
    }

    // ---- ring-exchange geometry (step-invariant) ----
    int  r_gofs[2], r_lofs[2];
    bool r_img[2];
    #pragma unroll
    for (int k = 0; k < 2; k++) {
        int u = tid + k * BLK;
        r_img[k] = false; r_gofs[k] = 0; r_lofs[k] = 0;
        if (u < 400) {
            int su = u >> 2, q4 = u & 3;
            int R, C;
            if (su < 80) { int rb = su / 20; R = (rb < 2) ? rb : rb + 5; C = su % 20; }
            else { int e = su - 80; R = 2 + (e >> 2); int ci = e & 3; C = (ci < 2) ? ci : ci + 16; }
            int gy = y0 - 2 + R, gx = x0 - 2 + C;
            r_lofs[k] = swz16((R * 20 + C) * 32 + q4 * 8);
            if (gy >= 0 && gy < Hn && gx >= 0 && gx < Wn) {
                r_img[k] = true;
                r_gofs[k] = (gy * Wn + gx) * 32 + q4 * 8;
            }
        }
    }

    // ---- phase-A geometry (halo tiles 2wid, 2wid+1), step-invariant ----
    int hs0 = (wid * 2) * 16 + n, hs1 = hs0 + 16;
    bool av0 = hs0 < 126, av1 = hs1 < 126;
    int hr0 = hs0 / 18, hc0 = hs0 - hr0 * 18;
    int hr1 = hs1 / 18, hc1 = hs1 - hr1 * 18;
    int gy0 = y0 - 1 + hr0, gx0 = x0 - 1 + hc0;
    int gy1 = y0 - 1 + hr1, gx1 = x0 - 1 + hc1;

    // hoisted x-load offsets/validity for phase A (chunks 0..2)
    int  xaofs[2][3]; bool xaok[2][3];
    #pragma unroll
    for (int c = 0; c < 3; c++) {
        int tap = c * 4 + q;
        #pragma unroll
        for (int k = 0; k < 2; k++) { xaok[k][c] = false; xaofs[k][c] = 0; }
        if (tap < 9) {
            int dy = tap / 3 - 1, dx = tap % 3 - 1;
            int ay0 = gy0 + dy, ax0 = gx0 + dx;
            int ay1 = gy1 + dy, ax1 = gx1 + dx;
            if (av0 && ay0 >= 0 && ay0 < Hn && ax0 >= 0 && ax0 < Wn) {
                xaok[0][c] = true; xaofs[0][c] = (ay0 * Wn + ax0) * 8;
            }
            if (av1 && ay1 >= 0 && ay1 < Hn && ax1 >= 0 && ax1 < Wn) {
                xaok[1][c] = true; xaofs[1][c] = (ay1 * Wn + ax1) * 8;
            }
        }
    }
    // hoisted pre-swizzled h_l offsets for phase-A h taps
    int hofs0[9], hofs1[9];
    {
        int hbase0 = ((hr0 + 1) * 20 + hc0 + 1) * 32 + q8;
        int hbase1 = ((hr1 + 1) * 20 + hc1 + 1) * 32 + q8;
        #pragma unroll
        for (int tap = 0; tap < 9; tap++) {
            int d = ((tap / 3 - 1) * 20 + (tap % 3 - 1)) * 32;
            hofs0[tap] = swz16(hbase0 + d);
            hofs1[tap] = swz16(hbase1 + d);
        }
    }

    // ---- phase-B geometry (interior tiles 2wid, 2wid+1 < 5), step-invariant ----
    int t0 = wid * 2;
    bool v0 = (t0 < 5), v1 = (t0 + 1 < 5);
    int tc0 = t0, tc1 = v1 ? t0 + 1 : t0;
    int yB0 = y0 + tc0, yB1 = y0 + tc1;

    int  xbofs[2][3]; bool xbok[2][3];
    #pragma unroll
    for (int c = 0; c < 3; c++) {
        int tap = c * 4 + q;
        #pragma unroll
        for (int k = 0; k < 2; k++) { xbok[k][c] = false; xbofs[k][c] = 0; }
        if (tap < 9) {
            int dy = tap / 3 - 1, dx = tap % 3 - 1;
            int ax = x0 + n + dx;
            int ay0 = yB0 + dy, ay1 = yB1 + dy;
            if (ay0 >= 0 && ay0 < Hn && ax >= 0 && ax < Wn) {
                xbok[0][c] = true; xbofs[0][c] = (ay0 * Wn + ax) * 8;
            }
            if (ay1 >= 0 && ay1 < Hn && ax >= 0 && ax < Wn) {
                xbok[1][c] = true; xbofs[1][c] = (ay1 * Wn + ax) * 8;
            }
        }
    }
    int rofs0[9], rofs1[9];
    #pragma unroll
    for (int tap = 0; tap < 9; tap++) {
        int ky = tap / 3, kx = tap % 3;
        rofs0[tap] = ((tc0 + ky) * 18 + n + kx) * 40 + q8;
        rofs1[tap] = ((tc1 + ky) * 18 + n + kx) * 40 + q8;
    }

    // hoisted bias values
    float bvA[4], bvB2[2];
    #pragma unroll
    for (int nt = 0; nt < 4; nt++) bvA[nt] = bias[nt * 16 + n];
    #pragma unroll
    for (int c = 0; c < 2; c++) bvB2[c] = bias[64 + c * 16 + n];

    // fp32 interior h state, register-resident across all steps
    f32x4 hst[2][2];
    #pragma unroll
    for (int a = 0; a < 2; a++)
        #pragma unroll
        for (int c = 0; c < 2; c++) hst[a][c] = (f32x4)0.f;

    float* hpub = z_l;   // overlay: epilogue B reads z then writes h into same slot

    __syncthreads();   // bA_l + h_l init ready

    #pragma unroll 1
    for (int s = 0; s < Tn; s++) {
        int t = dir ? (Tn - 1 - s) : s;
        const short* xs   = xb8 + (size_t)((b * Tn + t) * SITES) * 8;
        const short* hbpf = (s & 1) ? hfield0 : hfield1;
        short*       hbcf = (s & 1) ? hfield1 : hfield0;

        // ---- issue ALL x loads (phase A + phase B) before any waiting ----
        short8 xa[2][3], xb[2][3];
        #pragma unroll
        for (int c = 0; c < 3; c++) {
            xa[0][c] = xaok[0][c] ? *(const short8*)&xs[xaofs[0][c]] : (short8)(short)0;
            xa[1][c] = xaok[1][c] ? *(const short8*)&xs[xaofs[1][c]] : (short8)(short)0;
            xb[0][c] = xbok[0][c] ? *(const short8*)&xs[xbofs[0][c]] : (short8)(short)0;
            xb[1][c] = xbok[1][c] ? *(const short8*)&xs[xbofs[1][c]] : (short8)(short)0;
        }

        // ======== phase A, x part: chunks 0..2 — BEFORE the neighbor wait ========
        // Depends only on xa + bA_l (static): the flag-poll latency hides under it.
        f32x4 acc[2][4];
        #pragma unroll
        for (int nt = 0; nt < 4; nt++) {
            acc[0][nt] = (f32x4)bvA[nt]; acc[1][nt] = (f32x4)bvA[nt];
        }
        #pragma unroll
        for (int c = 0; c < 3; c++) {
            #pragma unroll
            for (int nt = 0; nt < 4; nt++) {
                short8 Bf = *(const short8*)&bA_l[((c * 4 + nt) * 64 + lane) * 8];
                acc[0][nt] = __builtin_amdgcn_mfma_f32_16x16x32_bf16(xa[0][c], Bf, acc[0][nt], 0, 0, 0);
                acc[1][nt] = __builtin_amdgcn_mfma_f32_16x16x32_bf16(xa[1][c], Bf, acc[1][nt], 0, 0, 0);
            }
        }

        // ---- wait for the 8 neighbors to have completed iter s-1 ----
        if (s > 0) {
            if (nflag) {
                unsigned spins = 0;
                while (__hip_atomic_load(nflag, __ATOMIC_RELAXED, __HIP_MEMORY_SCOPE_AGENT)
                       < (unsigned)s) {
                    __builtin_amdgcn_s_sleep(1);
                    if (++spins > (1u << 22)) break;
                }
            }
            __syncthreads();
        }

        // ---- ring prefetch (coherent, L3) + commit ----
        if (s > 0) {
            short8 rv0 = (short8)(short)0, rv1 = (short8)(short)0;
            if (r_img[0]) rv0 = h_load16(&hbpf[r_gofs[0]]);
            if (r_img[1]) rv1 = h_load16(&hbpf[r_gofs[1]]);
            if (r_img[0]) *(short8*)&h_l[r_lofs[0]] = rv0;
            if (r_img[1]) *(short8*)&h_l[r_lofs[1]] = rv1;
        }
        __syncthreads();   // h_l ring ready

        // ======== phase A, h part: taps 0..8 from LDS (pre-swizzled offsets) ========
        if (s > 0) {
            __builtin_amdgcn_s_setprio(1);
            #pragma unroll
            for (int tap = 0; tap < 9; tap++) {
                short8 a0 = *(const short8*)&h_l[hofs0[tap]];
                short8 a1 = *(const short8*)&h_l[hofs1[tap]];
                #pragma unroll
                for (int nt = 0; nt < 4; nt++) {
                    short8 Bf = *(const short8*)&bA_l[(((tap + 3) * 4 + nt) * 64 + lane) * 8];
                    acc[0][nt] = __builtin_amdgcn_mfma_f32_16x16x32_bf16(a0, Bf, acc[0][nt], 0, 0, 0);
                    acc[1][nt] = __builtin_amdgcn_mfma_f32_16x16x32_bf16(a1, Bf, acc[1][nt], 0, 0, 0);
                }
            }
            __builtin_amdgcn_s_setprio(0);
        }

        // epilogue A: z -> z_l (interior, stride ZSTR), r*h -> rh_l (all halo sites)
        #pragma unroll
        for (int tl = 0; tl < 2; tl++) {
            int ht = wid * 2 + tl;
            #pragma unroll
            for (int r = 0; r < 4; r++) {
                int hs_e = ht * 16 + q * 4 + r;
                if (hs_e >= 126) continue;
                int hr_e = hs_e / 18, hc_e = hs_e - hr_e * 18;
                bool inter = (hr_e >= 1 && hr_e <= 5 && hc_e >= 1 && hc_e <= 16);
                int gy_e = y0 - 1 + hr_e, gx_e = x0 - 1 + hc_e;
                bool img = (gy_e >= 0 && gy_e < Hn && gx_e >= 0 && gx_e < Wn);
                #pragma unroll
                for (int nt = 0; nt < 2; nt++) {
                    if (img && inter)
                        z_l[((hr_e - 1) * 16 + hc_e - 1) * ZSTR + nt * 16 + n] =
                            fast_sigmoid(acc[tl][nt][r]);
                }
                #pragma unroll
                for (int nt = 2; nt < 4; nt++) {
                    int ch = (nt - 2) * 16 + n;
                    float hv = bf2f(h_l[swz16(((hr_e + 1) * 20 + hc_e + 1) * 32 + ch)]);
                    float rhv = fast_sigmoid(acc[tl][nt][r]) * hv;
                    rh_l[hs_e * 40 + ch] = f2bf(rhv);
                }
            }
        }
        __syncthreads();

        // ======== phase B: candidate MFMA + epilogue B (no intervening barrier) ========
        if (v0) {
            f32x4 acc2[2][2];
            #pragma unroll
            for (int ntc = 0; ntc < 2; ntc++) {
                acc2[0][ntc] = (f32x4)bvB2[ntc]; acc2[1][ntc] = (f32x4)bvB2[ntc];
            }
            __builtin_amdgcn_s_setprio(1);
            #pragma unroll
            for (int chunk = 0; chunk < 12; chunk++) {
                short8 a0, a1;
                if (chunk < 3) {
                    a0 = xb[0][chunk];
                    a1 = xb[1][chunk];
                } else {
                    a0 = *(const short8*)&rh_l[rofs0[chunk - 3]];
                    a1 = *(const short8*)&rh_l[rofs1[chunk - 3]];
                }
                #pragma unroll
                for (int ntc = 0; ntc < 2; ntc++) {
                    short8 Bf = *(const short8*)&bB[((chunk * 2 + ntc) * 64 + lane) * 8];
                    acc2[0][ntc] = __builtin_amdgcn_mfma_f32_16x16x32_bf16(a0, Bf, acc2[0][ntc], 0, 0, 0);
                    acc2[1][ntc] = __builtin_amdgcn_mfma_f32_16x16x32_bf16(a1, Bf, acc2[1][ntc], 0, 0, 0);
                }
            }
            __builtin_amdgcn_s_setprio(0);

            // epilogue B: h = z*h_prev + (1-z)*tanh(.) -> hst regs + hpub (z_l overlay)
            // Thread reads z[slot] then writes h into the SAME slot (bijective);
            // concurrent waves in phase B read only rh_l -> no barrier needed here.
            #pragma unroll
            for (int tl = 0; tl < 2; tl++) {
                if (tl == 1 && !v1) continue;
                int ti = t0 + tl;
                #pragma unroll
                for (int ntc = 0; ntc < 2; ntc++) {
                    f32x4 hp = hst[tl][ntc];
                    f32x4 hn;
                    #pragma unroll
                    for (int r = 0; r < 4; r++) {
                        int slot = (ti * 16 + q * 4 + r) * ZSTR + ntc * 16 + n;
                        float z  = z_l[slot];
                        float hh = fast_tanh(acc2[tl][ntc][r]);
                        hn[r] = z * hp[r] + (1.f - z) * hh;
                        hpub[slot] = hn[r];
                    }
                    hst[tl][ntc] = hn;
                }
            }
        }
        __syncthreads();   // hpub ready

        // ======== publish: vectorized h (guarded gx<Wn) BEFORE flag ========
        if (s + 1 < Tn) {
            #pragma unroll
            for (int j = 0; j < 2; j++) {
                int u = tid + j * BLK;
                if (u < 320) {
                    int us = u >> 2, up = u & 3;       // site 0..79, 8-channel quarter
                    int row = us >> 4, col = us & 15;
                    int gx = x0 + col;
                    if (gx < Wn) {                     // Wn=120 is NOT a multiple of 16!
                        short8 hv8;
                        #pragma unroll
                        for (int e = 0; e < 8; e++)
                            hv8[e] = f2bf(hpub[us * ZSTR + up * 8 + e]);
                        *(short8*)&h_l[swz16(((row + 2) * 20 + col + 2) * 32 + up * 8)] = hv8;
                        h_store16(&hbcf[(size_t)((y0 + row) * Wn + gx) * 32 + up * 8], hv8);
                    }
                }
            }
            asm volatile("s_waitcnt vmcnt(0)" ::: "memory");
            __syncthreads();
            if (tid == 0)
                __hip_atomic_store(myflag, (unsigned)(s + 1),
                                   __ATOMIC_RELAXED, __HIP_MEMORY_SCOPE_AGENT);
        }

        // ======== out stores AFTER flag (HBM ack off the critical path) ========
        {
            size_t outb = (size_t)((b * Tn + t) * SITES) * 64 + dir * 32;
            #pragma unroll
            for (int j = 0; j < 3; j++) {
                int u = tid + j * BLK;
                if (u < 640) {
                    int us = u >> 3, up = u & 7;       // site 0..79, 4-float chunk
                    int row = us >> 4, col = us & 15;
                    int gx = x0 + col;
                    if (gx < Wn) {
                        f32x4 v;
                        #pragma unroll
                        for (int e = 0; e < 4; e++)
                            v[e] = hpub[us * ZSTR + up * 4 + e];
                        __builtin_nontemporal_store(v,
                            (f32x4*)&out[outb + (size_t)((y0 + row) * Wn + gx) * 64 + up * 4]);
                    }
                }
            }
        }
        // hpub (=z_l) is rewritten only in next step's epilogue A, which is
        // after the neighbor-wait + ring barriers: reads above are safely ordered.
    }
}

extern "C" void kernel_launch(void* const* d_in, const int* in_sizes, int n_in,
                              void* d_out, int out_size, void* d_ws, size_t ws_size,
                              hipStream_t stream)
{
    const float* x     = (const float*)d_in[0];
    const float* Wx_f  = (const float*)d_in[1];
    const float* b_f   = (const float*)d_in[2];
    const float* Wzr_f = (const float*)d_in[3];
    const float* Wh_f  = (const float*)d_in[4];
    const float* Wx_b  = (const float*)d_in[5];
    const float* b_b   = (const float*)d_in[6];
    const float* Wzr_b = (const float*)d_in[7];
    const float* Wh_b  = (const float*)d_in[8];
    float* out = (float*)d_out;

    char* w = (char*)d_ws;
    short* hb0  = (short*)w;  w += (size_t)HSZ * 2;
    short* hb1  = (short*)w;  w += (size_t)HSZ * 2;
    short* xb8  = (short*)w;  w += (size_t)NPX * 8 * 2;
    short* bopA = (short*)w;  w += (size_t)NA * 2;
    short* bopB = (short*)w;  w += (size_t)NB * 2;
    unsigned* flags = (unsigned*)w; w += (size_t)GRID * 32 * 4;
    // total ~8.9 MB

    prep_kernel<<<(PREP_TOT + BLK - 1) / BLK, BLK, 0, stream>>>(
        Wzr_f, Wzr_b, Wh_f, Wh_b, Wx_f, Wx_b, x, bopA, bopB, xb8, flags);

    step_all<<<GRID, BLK, 0, stream>>>(xb8, bopA, bopB, b_f, b_b,
                                       hb0, hb1, out, flags);
}

// Round 17
// 202.168 us; speedup vs baseline: 1.0647x; 1.0647x over previous
//
#include <hip/hip_runtime.h>
#include <hip/hip_bf16.h>

#define Bn 2
#define Tn 12
#define Hn 80
#define Wn 120
#define CIN 6
#define SITES (Hn * Wn)          // 9600
#define HSZ (4 * SITES * 32)     // 1228800 elements per bf16 state field
#define GRID 512                 // 4 fields x 16 yb x 8 seg  (= 2 blocks/CU, all co-resident)
#define BLK 256

#define NA_D (48 * 64 * 8)       // gates operand-order B set, per dir (24576 shorts)
#define NB_D (24 * 64 * 8)       // candidate set per dir (12288 shorts)
#define NA (2 * NA_D)
#define NB (2 * NB_D)
#define NPX (Bn * Tn * SITES)
#define PREP_TOT (NA + NB + NPX) // 304128

#define ZSTR 34                  // z_l/hpub site stride (floats): bank=(2*site+ch)%32 -> 2-way

typedef __attribute__((ext_vector_type(8))) short short8;
typedef __attribute__((ext_vector_type(4))) float f32x4;

__device__ __forceinline__ short f2bf(float f) {
    union { __hip_bfloat16 h; short s; } u;
    u.h = __float2bfloat16(f);
    return u.s;
}
__device__ __forceinline__ float bf2f(short s) {
    union { float f; unsigned u; } u;
    u.u = ((unsigned)(unsigned short)s) << 16;
    return u.f;
}
// v_rcp_f32-based (~1ulp): full fp32 divide is ~10 instrs of div_scale/fmas/fixup
__device__ __forceinline__ float fast_sigmoid(float v) {
    return __builtin_amdgcn_rcpf(1.f + __expf(-v));
}
__device__ __forceinline__ float fast_tanh(float v) {
    v = fminf(fmaxf(v, -15.f), 15.f);
    float e = __expf(2.f * v);
    return (e - 1.f) * __builtin_amdgcn_rcpf(e + 1.f);
}

// ---- coherent (L2-bypass) h-state access: agent-scope relaxed atomics ----
__device__ __forceinline__ short8 h_load16(const short* p) {
    union { unsigned long long q[2]; short8 v; } u;
    u.q[0] = __hip_atomic_load((const unsigned long long*)p,
                               __ATOMIC_RELAXED, __HIP_MEMORY_SCOPE_AGENT);
    u.q[1] = __hip_atomic_load((const unsigned long long*)(p + 4),
                               __ATOMIC_RELAXED, __HIP_MEMORY_SCOPE_AGENT);
    return u.v;
}
__device__ __forceinline__ void h_store16(short* p, short8 v) {
    union { short8 v; unsigned long long q[2]; } u; u.v = v;
    __hip_atomic_store((unsigned long long*)p, u.q[0],
                       __ATOMIC_RELAXED, __HIP_MEMORY_SCOPE_AGENT);
    __hip_atomic_store((unsigned long long*)(p + 4), u.q[1],
                       __ATOMIC_RELAXED, __HIP_MEMORY_SCOPE_AGENT);
}

// ---- h_l LDS bank-conflict swizzle (bijective; applied to all h_l accesses) ----
__device__ __forceinline__ int swz16(int i) { return i ^ (((i >> 5) & 7) << 3); }

// ---- prologue: expand weights to MFMA-operand order + pack x to padded bf16x8 ----
__global__ __launch_bounds__(BLK) void prep_kernel(
    const float* __restrict__ Wzr_f, const float* __restrict__ Wzr_b,
    const float* __restrict__ Wh_f,  const float* __restrict__ Wh_b,
    const float* __restrict__ Wx_f,  const float* __restrict__ Wx_b,
    const float* __restrict__ x,
    short* __restrict__ bopA, short* __restrict__ bopB, short* __restrict__ xb8,
    unsigned* __restrict__ flags)
{
    int i = blockIdx.x * BLK + threadIdx.x;
    if (i < GRID) flags[i << 5] = 0;   // reset per-block step flags each replay
    if (i < NA) {
        int dir = i / NA_D; int r = i % NA_D;
        int f = r / 512; int lane = (r % 512) / 8; int j = r % 8;
        int q = lane >> 4, n = lane & 15;
        int chunk = f >> 2, nt = f & 3;
        float v = 0.f;
        if (chunk < 3) {
            int tap = chunk * 4 + q;
            if (tap < 9 && j < 6) v = (dir ? Wx_b : Wx_f)[(tap * CIN + j) * 96 + nt * 16 + n];
        } else {
            int tap = chunk - 3;
            v = (dir ? Wzr_b : Wzr_f)[(tap * 32 + q * 8 + j) * 64 + nt * 16 + n];
        }
        bopA[i] = f2bf(v);
    } else if (i < NA + NB) {
        int ii = i - NA;
        int dir = ii / NB_D; int r = ii % NB_D;
        int f = r / 512; int lane = (r % 512) / 8; int j = r % 8;
        int q = lane >> 4, n = lane & 15;
        int chunk = f >> 1, ntc = f & 1;
        float v = 0.f;
        if (chunk < 3) {
            int tap = chunk * 4 + q;
            if (tap < 9 && j < 6) v = (dir ? Wx_b : Wx_f)[(tap * CIN + j) * 96 + 64 + ntc * 16 + n];
        } else {
            int tap = chunk - 3;
            v = (dir ? Wh_b : Wh_f)[(tap * 32 + q * 8 + j) * 32 + ntc * 16 + n];
        }
        bopB[ii] = f2bf(v);
    } else if (i < PREP_TOT) {
        int p = i - NA - NB;
        const float* xp = x + (size_t)p * CIN;
        short v[8];
        #pragma unroll
        for (int c = 0; c < CIN; c++) v[c] = f2bf(xp[c]);
        v[6] = 0; v[7] = 0;
        *(short8*)&xb8[(size_t)p * 8] = *(short8*)v;
    }
}

// ---- persistent fused GRU, neighbor-local synchronization (round-14 = best) ----
// LDS: bA 48K + rh 10080 + z/hpub 10880 + h-tile 11520 = 81632 B -> 2 blocks/CU.
// Step ordering (verified fastest): issue x loads -> wait -> issue ring load ->
// x-part MFMA (hides ring L3 latency) -> commit ring -> barrier -> h-part MFMA.
__global__ __launch_bounds__(BLK, 2) void step_all(
    const short* __restrict__ xb8,
    const short* __restrict__ bopA, const short* __restrict__ bopB,
    const float* __restrict__ b_f, const float* __restrict__ b_b,
    short* __restrict__ hb0, short* __restrict__ hb1,
    float* __restrict__ out, unsigned* __restrict__ flags)
{
    __shared__ __align__(16) short bA_l[NA_D];        // 49152 B
    __shared__ __align__(16) short rh_l[126 * 40];    // 10080 B (r*h bf16, halo 7x18)
    __shared__ __align__(16) float z_l[80 * ZSTR];    // 10880 B (z fp32 | hpub overlay)
    __shared__ __align__(16) short h_l[9 * 20 * 32];  // 11520 B (swizzled)

    int tid = threadIdx.x, bid = blockIdx.x;
    int seg = bid & 7;
    int t1  = bid >> 3;
    int yb  = t1 & 15;
    int field = t1 >> 4;
    int dir = field >> 1, b = field & 1;
    int y0 = yb * 5, x0 = seg * 16;

    // stage this-direction gate B-set into LDS once
    {
        const short* src = bopA + dir * NA_D;
        #pragma unroll
        for (int it = 0; it < NA_D / (BLK * 8); it++) {
            int i = (it * BLK + tid) * 8;
            *(short8*)&bA_l[i] = *(const short8*)&src[i];
        }
    }
    // zero-init h tile (out-of-image sites rely on staying zero forever)
    for (int c = tid; c < 720; c += BLK) *(short8*)&h_l[c * 8] = (short8)(short)0;

    const short* bB   = bopB + dir * NB_D;
    const float* bias = dir ? b_b : b_f;
    short* hfield0 = hb0 + (size_t)field * SITES * 32;
    short* hfield1 = hb1 + (size_t)field * SITES * 32;

    int wid = tid >> 6, lane = tid & 63;
    int n = lane & 15, q = lane >> 4, q8 = q * 8;

    // ---- neighbor flags ----
    unsigned* myflag = flags + (bid << 5);
    const unsigned* nflag = nullptr;
    if (tid < 8) {
        int k = tid + (tid >= 4);
        int ny = yb + k / 3 - 1, nx = seg + k % 3 - 1;
        if (ny >= 0 && ny < 16 && nx >= 0 && nx < 8)
            nflag = flags + ((unsigned)((field << 7) | (ny << 3) | nx) << 5);
    }

    // ---- ring-exchange geometry (step-invariant) ----
    int  r_gofs[2], r_lofs[2];
    bool r_img[2];
    #pragma unroll
    for (int k = 0; k < 2; k++) {
        int u = tid + k * BLK;
        r_img[k] = false; r_gofs[k] = 0; r_lofs[k] = 0;
        if (u < 400) {
            int su = u >> 2, q4 = u & 3;
            int R, C;
            if (su < 80) { int rb = su / 20; R = (rb < 2) ? rb : rb + 5; C = su % 20; }
            else { int e = su - 80; R = 2 + (e >> 2); int ci = e & 3; C = (ci < 2) ? ci : ci + 16; }
            int gy = y0 - 2 + R, gx = x0 - 2 + C;
            r_lofs[k] = swz16((R * 20 + C) * 32 + q4 * 8);
            if (gy >= 0 && gy < Hn && gx >= 0 && gx < Wn) {
                r_img[k] = true;
                r_gofs[k] = (gy * Wn + gx) * 32 + q4 * 8;
            }
        }
    }

    // ---- phase-A geometry (halo tiles 2wid, 2wid+1), step-invariant ----
    int hs0 = (wid * 2) * 16 + n, hs1 = hs0 + 16;
    bool av0 = hs0 < 126, av1 = hs1 < 126;
    int hr0 = hs0 / 18, hc0 = hs0 - hr0 * 18;
    int hr1 = hs1 / 18, hc1 = hs1 - hr1 * 18;
    int gy0 = y0 - 1 + hr0, gx0 = x0 - 1 + hc0;
    int gy1 = y0 - 1 + hr1, gx1 = x0 - 1 + hc1;

    // hoisted x-load offsets/validity for phase A (chunks 0..2)
    int  xaofs[2][3]; bool xaok[2][3];
    #pragma unroll
    for (int c = 0; c < 3; c++) {
        int tap = c * 4 + q;
        #pragma unroll
        for (int k = 0; k < 2; k++) { xaok[k][c] = false; xaofs[k][c] = 0; }
        if (tap < 9) {
            int dy = tap / 3 - 1, dx = tap % 3 - 1;
            int ay0 = gy0 + dy, ax0 = gx0 + dx;
            int ay1 = gy1 + dy, ax1 = gx1 + dx;
            if (av0 && ay0 >= 0 && ay0 < Hn && ax0 >= 0 && ax0 < Wn) {
                xaok[0][c] = true; xaofs[0][c] = (ay0 * Wn + ax0) * 8;
            }
            if (av1 && ay1 >= 0 && ay1 < Hn && ax1 >= 0 && ax1 < Wn) {
                xaok[1][c] = true; xaofs[1][c] = (ay1 * Wn + ax1) * 8;
            }
        }
    }
    // hoisted pre-swizzled h_l offsets for phase-A h taps
    int hofs0[9], hofs1[9];
    {
        int hbase0 = ((hr0 + 1) * 20 + hc0 + 1) * 32 + q8;
        int hbase1 = ((hr1 + 1) * 20 + hc1 + 1) * 32 + q8;
        #pragma unroll
        for (int tap = 0; tap < 9; tap++) {
            int d = ((tap / 3 - 1) * 20 + (tap % 3 - 1)) * 32;
            hofs0[tap] = swz16(hbase0 + d);
            hofs1[tap] = swz16(hbase1 + d);
        }
    }

    // ---- phase-B geometry (interior tiles 2wid, 2wid+1 < 5), step-invariant ----
    int t0 = wid * 2;
    bool v0 = (t0 < 5), v1 = (t0 + 1 < 5);
    int tc0 = t0, tc1 = v1 ? t0 + 1 : t0;
    int yB0 = y0 + tc0, yB1 = y0 + tc1;

    int  xbofs[2][3]; bool xbok[2][3];
    #pragma unroll
    for (int c = 0; c < 3; c++) {
        int tap = c * 4 + q;
        #pragma unroll
        for (int k = 0; k < 2; k++) { xbok[k][c] = false; xbofs[k][c] = 0; }
        if (tap < 9) {
            int dy = tap / 3 - 1, dx = tap % 3 - 1;
            int ax = x0 + n + dx;
            int ay0 = yB0 + dy, ay1 = yB1 + dy;
            if (ay0 >= 0 && ay0 < Hn && ax >= 0 && ax < Wn) {
                xbok[0][c] = true; xbofs[0][c] = (ay0 * Wn + ax) * 8;
            }
            if (ay1 >= 0 && ay1 < Hn && ax >= 0 && ax < Wn) {
                xbok[1][c] = true; xbofs[1][c] = (ay1 * Wn + ax) * 8;
            }
        }
    }
    int rofs0[9], rofs1[9];
    #pragma unroll
    for (int tap = 0; tap < 9; tap++) {
        int ky = tap / 3, kx = tap % 3;
        rofs0[tap] = ((tc0 + ky) * 18 + n + kx) * 40 + q8;
        rofs1[tap] = ((tc1 + ky) * 18 + n + kx) * 40 + q8;
    }

    // hoisted bias values
    float bvA[4], bvB2[2];
    #pragma unroll
    for (int nt = 0; nt < 4; nt++) bvA[nt] = bias[nt * 16 + n];
    #pragma unroll
    for (int c = 0; c < 2; c++) bvB2[c] = bias[64 + c * 16 + n];

    // fp32 interior h state, register-resident across all steps
    f32x4 hst[2][2];
    #pragma unroll
    for (int a = 0; a < 2; a++)
        #pragma unroll
        for (int c = 0; c < 2; c++) hst[a][c] = (f32x4)0.f;

    float* hpub = z_l;   // overlay: epilogue B reads z then writes h into same slot

    __syncthreads();   // bA_l + h_l init ready

    #pragma unroll 1
    for (int s = 0; s < Tn; s++) {
        int t = dir ? (Tn - 1 - s) : s;
        const short* xs   = xb8 + (size_t)((b * Tn + t) * SITES) * 8;
        const short* hbpf = (s & 1) ? hfield0 : hfield1;
        short*       hbcf = (s & 1) ? hfield1 : hfield0;

        // ---- issue phase-A x loads BEFORE the neighbor wait (latency hidden) ----
        short8 xa[2][3];
        #pragma unroll
        for (int c = 0; c < 3; c++) {
            xa[0][c] = xaok[0][c] ? *(const short8*)&xs[xaofs[0][c]] : (short8)(short)0;
            xa[1][c] = xaok[1][c] ? *(const short8*)&xs[xaofs[1][c]] : (short8)(short)0;
        }

        // ---- wait for the 8 neighbors to have completed iter s-1 ----
        if (s > 0) {
            if (nflag) {
                unsigned spins = 0;
                while (__hip_atomic_load(nflag, __ATOMIC_RELAXED, __HIP_MEMORY_SCOPE_AGENT)
                       < (unsigned)s) {
                    __builtin_amdgcn_s_sleep(1);
                    if (++spins > (1u << 22)) break;
                }
            }
            __syncthreads();
        }

        // ---- ring prefetch (coherent, L3) ----
        short8 rv0 = (short8)(short)0, rv1 = (short8)(short)0;
        if (s > 0) {
            if (r_img[0]) rv0 = h_load16(&hbpf[r_gofs[0]]);
            if (r_img[1]) rv1 = h_load16(&hbpf[r_gofs[1]]);
        }

        // ======== phase A, x part: chunks 0..2 (hides ring latency) ========
        f32x4 acc[2][4];
        #pragma unroll
        for (int nt = 0; nt < 4; nt++) {
            acc[0][nt] = (f32x4)bvA[nt]; acc[1][nt] = (f32x4)bvA[nt];
        }
        #pragma unroll
        for (int c = 0; c < 3; c++) {
            #pragma unroll
            for (int nt = 0; nt < 4; nt++) {
                short8 Bf = *(const short8*)&bA_l[((c * 4 + nt) * 64 + lane) * 8];
                acc[0][nt] = __builtin_amdgcn_mfma_f32_16x16x32_bf16(xa[0][c], Bf, acc[0][nt], 0, 0, 0);
                acc[1][nt] = __builtin_amdgcn_mfma_f32_16x16x32_bf16(xa[1][c], Bf, acc[1][nt], 0, 0, 0);
            }
        }

        // ---- commit ring to h tile ----
        if (s > 0) {
            if (r_img[0]) *(short8*)&h_l[r_lofs[0]] = rv0;
            if (r_img[1]) *(short8*)&h_l[r_lofs[1]] = rv1;
        }
        __syncthreads();   // h_l ring ready

        // ======== phase A, h part: taps 0..8 from LDS (pre-swizzled offsets) ========
        if (s > 0) {
            __builtin_amdgcn_s_setprio(1);
            #pragma unroll
            for (int tap = 0; tap < 9; tap++) {
                short8 a0 = *(const short8*)&h_l[hofs0[tap]];
                short8 a1 = *(const short8*)&h_l[hofs1[tap]];
                #pragma unroll
                for (int nt = 0; nt < 4; nt++) {
                    short8 Bf = *(const short8*)&bA_l[(((tap + 3) * 4 + nt) * 64 + lane) * 8];
                    acc[0][nt] = __builtin_amdgcn_mfma_f32_16x16x32_bf16(a0, Bf, acc[0][nt], 0, 0, 0);
                    acc[1][nt] = __builtin_amdgcn_mfma_f32_16x16x32_bf16(a1, Bf, acc[1][nt], 0, 0, 0);
                }
            }
            __builtin_amdgcn_s_setprio(0);
        }

        // epilogue A: z -> z_l (interior, stride ZSTR), r*h -> rh_l (all halo sites)
        #pragma unroll
        for (int tl = 0; tl < 2; tl++) {
            int ht = wid * 2 + tl;
            #pragma unroll
            for (int r = 0; r < 4; r++) {
                int hs_e = ht * 16 + q * 4 + r;
                if (hs_e >= 126) continue;
                int hr_e = hs_e / 18, hc_e = hs_e - hr_e * 18;
                bool inter = (hr_e >= 1 && hr_e <= 5 && hc_e >= 1 && hc_e <= 16);
                int gy_e = y0 - 1 + hr_e, gx_e = x0 - 1 + hc_e;
                bool img = (gy_e >= 0 && gy_e < Hn && gx_e >= 0 && gx_e < Wn);
                #pragma unroll
                for (int nt = 0; nt < 2; nt++) {
                    if (img && inter)
                        z_l[((hr_e - 1) * 16 + hc_e - 1) * ZSTR + nt * 16 + n] =
                            fast_sigmoid(acc[tl][nt][r]);
                }
                #pragma unroll
                for (int nt = 2; nt < 4; nt++) {
                    int ch = (nt - 2) * 16 + n;
                    float hv = bf2f(h_l[swz16(((hr_e + 1) * 20 + hc_e + 1) * 32 + ch)]);
                    float rhv = fast_sigmoid(acc[tl][nt][r]) * hv;
                    rh_l[hs_e * 40 + ch] = f2bf(rhv);
                }
            }
        }
        __syncthreads();

        // ======== phase B: candidate MFMA + epilogue B (no intervening barrier) ========
        if (v0) {
            f32x4 acc2[2][2];
            #pragma unroll
            for (int ntc = 0; ntc < 2; ntc++) {
                acc2[0][ntc] = (f32x4)bvB2[ntc]; acc2[1][ntc] = (f32x4)bvB2[ntc];
            }
            __builtin_amdgcn_s_setprio(1);
            #pragma unroll
            for (int chunk = 0; chunk < 12; chunk++) {
                short8 a0, a1;
                if (chunk < 3) {
                    a0 = xbok[0][chunk] ? *(const short8*)&xs[xbofs[0][chunk]] : (short8)(short)0;
                    a1 = xbok[1][chunk] ? *(const short8*)&xs[xbofs[1][chunk]] : (short8)(short)0;
                } else {
                    a0 = *(const short8*)&rh_l[rofs0[chunk - 3]];
                    a1 = *(const short8*)&rh_l[rofs1[chunk - 3]];
                }
                #pragma unroll
                for (int ntc = 0; ntc < 2; ntc++) {
                    short8 Bf = *(const short8*)&bB[((chunk * 2 + ntc) * 64 + lane) * 8];
                    acc2[0][ntc] = __builtin_amdgcn_mfma_f32_16x16x32_bf16(a0, Bf, acc2[0][ntc], 0, 0, 0);
                    acc2[1][ntc] = __builtin_amdgcn_mfma_f32_16x16x32_bf16(a1, Bf, acc2[1][ntc], 0, 0, 0);
                }
            }
            __builtin_amdgcn_s_setprio(0);

            // epilogue B: h = z*h_prev + (1-z)*tanh(.) -> hst regs + hpub (z_l overlay)
            // Thread reads z[slot] then writes h into the SAME slot (bijective);
            // concurrent waves in phase B read only rh_l -> no barrier needed here.
            #pragma unroll
            for (int tl = 0; tl < 2; tl++) {
                if (tl == 1 && !v1) continue;
                int ti = t0 + tl;
                #pragma unroll
                for (int ntc = 0; ntc < 2; ntc++) {
                    f32x4 hp = hst[tl][ntc];
                    f32x4 hn;
                    #pragma unroll
                    for (int r = 0; r < 4; r++) {
                        int slot = (ti * 16 + q * 4 + r) * ZSTR + ntc * 16 + n;
                        float z  = z_l[slot];
                        float hh = fast_tanh(acc2[tl][ntc][r]);
                        hn[r] = z * hp[r] + (1.f - z) * hh;
                        hpub[slot] = hn[r];
                    }
                    hst[tl][ntc] = hn;
                }
            }
        }
        __syncthreads();   // hpub ready

        // ======== publish: vectorized h (guarded gx<Wn) BEFORE flag ========
        if (s + 1 < Tn) {
            #pragma unroll
            for (int j = 0; j < 2; j++) {
                int u = tid + j * BLK;
                if (u < 320) {
                    int us = u >> 2, up = u & 3;       // site 0..79, 8-channel quarter
                    int row = us >> 4, col = us & 15;
                    int gx = x0 + col;
                    if (gx < Wn) {                     // Wn=120 is NOT a multiple of 16!
                        short8 hv8;
                        #pragma unroll
                        for (int e = 0; e < 8; e++)
                            hv8[e] = f2bf(hpub[us * ZSTR + up * 8 + e]);
                        *(short8*)&h_l[swz16(((row + 2) * 20 + col + 2) * 32 + up * 8)] = hv8;
                        h_store16(&hbcf[(size_t)((y0 + row) * Wn + gx) * 32 + up * 8], hv8);
                    }
                }
            }
            asm volatile("s_waitcnt vmcnt(0)" ::: "memory");
            __syncthreads();
            if (tid == 0)
                __hip_atomic_store(myflag, (unsigned)(s + 1),
                                   __ATOMIC_RELAXED, __HIP_MEMORY_SCOPE_AGENT);
        }

        // ======== out stores AFTER flag (HBM ack off the critical path) ========
        {
            size_t outb = (size_t)((b * Tn + t) * SITES) * 64 + dir * 32;
            #pragma unroll
            for (int j = 0; j < 3; j++) {
                int u = tid + j * BLK;
                if (u < 640) {
                    int us = u >> 3, up = u & 7;       // site 0..79, 4-float chunk
                    int row = us >> 4, col = us & 15;
                    int gx = x0 + col;
                    if (gx < Wn) {
                        f32x4 v;
                        #pragma unroll
                        for (int e = 0; e < 4; e++)
                            v[e] = hpub[us * ZSTR + up * 4 + e];
                        __builtin_nontemporal_store(v,
                            (f32x4*)&out[outb + (size_t)((y0 + row) * Wn + gx) * 64 + up * 4]);
                    }
                }
            }
        }
        // hpub (=z_l) is rewritten only in next step's epilogue A, which is
        // after the neighbor-wait + ring barriers: reads above are safely ordered.
    }
}

extern "C" void kernel_launch(void* const* d_in, const int* in_sizes, int n_in,
                              void* d_out, int out_size, void* d_ws, size_t ws_size,
                              hipStream_t stream)
{
    const float* x     = (const float*)d_in[0];
    const float* Wx_f  = (const float*)d_in[1];
    const float* b_f   = (const float*)d_in[2];
    const float* Wzr_f = (const float*)d_in[3];
    const float* Wh_f  = (const float*)d_in[4];
    const float* Wx_b  = (const float*)d_in[5];
    const float* b_b   = (const float*)d_in[6];
    const float* Wzr_b = (const float*)d_in[7];
    const float* Wh_b  = (const float*)d_in[8];
    float* out = (float*)d_out;

    char* w = (char*)d_ws;
    short* hb0  = (short*)w;  w += (size_t)HSZ * 2;
    short* hb1  = (short*)w;  w += (size_t)HSZ * 2;
    short* xb8  = (short*)w;  w += (size_t)NPX * 8 * 2;
    short* bopA = (short*)w;  w += (size_t)NA * 2;
    short* bopB = (short*)w;  w += (size_t)NB * 2;
    unsigned* flags = (unsigned*)w; w += (size_t)GRID * 32 * 4;
    // total ~8.9 MB

    prep_kernel<<<(PREP_TOT + BLK - 1) / BLK, BLK, 0, stream>>>(
        Wzr_f, Wzr_b, Wh_f, Wh_b, Wx_f, Wx_b, x, bopA, bopB, xb8, flags);

    step_all<<<GRID, BLK, 0, stream>>>(xb8, bopA, bopB, b_f, b_b,
                                       hb0, hb1, out, flags);
}